// Round 1
// 938.202 us; speedup vs baseline: 3.5239x; 3.5239x over previous
//
// v9: restructured. XXT = x@x^T (bf16) precomputed by GEMM into d_out (each
// attn block reads only its OWN 16 XXT rows == the exact bytes of its own
// final out rows -> no workspace, no race). V stored TRANSPOSED (computed as
// wv @ x^T, plain NT GEMM). attn: 256 blocks x 512 thr (8 waves, 2 heads per
// wave), 32-key tiles, two-pass exact softmax; K/V/bias read DIRECT from
// global (L2) -- no K/V LDS staging; pass 1 touches no LDS / no barriers;
// pass 2 has 2 barriers/iter (cross-wave PS reduce only). Only x^T is staged
// (wave-private, bank-swizzled). XXT diagonal recomputed exactly in-kernel
// (bf16 rounding at |x.x|~1024 would put ~0.2 on sv).
#include <hip/hip_runtime.h>

typedef unsigned short u16;
typedef unsigned int   u32;
typedef unsigned char  u8;
typedef __attribute__((ext_vector_type(8))) short          short8;
typedef __attribute__((ext_vector_type(8))) unsigned short ushort8;
typedef __attribute__((ext_vector_type(4))) float          f32x4;

#define MFMA(a,b,c) __builtin_amdgcn_mfma_f32_16x16x32_bf16((a),(b),(c),0,0,0)
#define Nx 2048
#define Dx 1024
#define SCALEx 0.125f

__device__ __forceinline__ float bf2f(u16 u){ u32 x=((u32)u)<<16; return __builtin_bit_cast(float,x); }
__device__ __forceinline__ u16 f2bf(float f){ u32 u=__builtin_bit_cast(u32,f); u32 r=(u+0x7FFFu+((u>>16)&1u))>>16; return (u16)r; }
__device__ __forceinline__ short8 lds8(const u16* p){ return *(const short8*)p; }

// ---- dtype normalization (identity if already bf16) ----
__device__ int looks_bf16_dev(const u16* p, int nsamp, float lo, float hi){
  int cnt = 0;
  for (int i = 0; i < nsamp; ++i){
    float a = fabsf(bf2f(p[2*i]));
    if (a >= lo && a <= hi) cnt++;
  }
  return (2*cnt > nsamp) ? 1 : 0;
}

__global__ __launch_bounds__(256) void conv_w(const void* __restrict__ in, u16* __restrict__ S,
                                              int n, int nsamp, float lo, float hi){
  __shared__ int flag;
  if (threadIdx.x == 0) flag = looks_bf16_dev((const u16*)in, nsamp, lo, hi);
  __syncthreads();
  const int isbf = flag;
  int i = blockIdx.x*256 + threadIdx.x;
  int stride = gridDim.x*256;
  if (isbf){
    const u16* pu = (const u16*)in;
    for (; i < n; i += stride) S[i] = pu[i];
  } else {
    const float* pf = (const float*)in;
    for (; i < n; i += stride) S[i] = f2bf(pf[i]);
  }
}

__global__ __launch_bounds__(256) void copyb(const u16* __restrict__ S, u16* __restrict__ dst, int n){
  int i = blockIdx.x*256 + threadIdx.x;
  int stride = gridDim.x*256;
  for (; i < n; i += stride) dst[i] = S[i];
}

__global__ void conv_small(void* buf, int n, float lo, float hi){
  __shared__ float tmp[64];
  __shared__ int flag;
  int t = threadIdx.x;
  if (t == 0) flag = looks_bf16_dev((const u16*)buf, n/2, lo, hi);
  __syncthreads();
  if (t < n) tmp[t] = flag ? bf2f(((const u16*)buf)[t]) : ((const float*)buf)[t];
  __syncthreads();
  if (t < n) ((u16*)buf)[t] = f2bf(tmp[t]);
}

// ---------------------------------------------------------------------------
// NT GEMM bf16: C[M][ldc] = A[M][1024] @ Bt[N][1024]^T  (M = grid.y*128,
// N = grid.x*128, K = 1024, lda = ldb = 1024, ldc runtime).
// ---------------------------------------------------------------------------
__global__ __launch_bounds__(256) void gemm_bf16(
    const u16* __restrict__ A, const u16* __restrict__ Bt, u16* __restrict__ C, int ldc)
{
  const int tid = threadIdx.x;
  const int lane = tid & 63, wave = tid >> 6;
  const int wm = wave >> 1, wn = wave & 1;
  const int l15 = lane & 15, quad = lane >> 4;
  const int m0 = blockIdx.y * 128, n0 = blockIdx.x * 128;
  __shared__ u16 As[128*32], Bs[128*32];
  f32x4 acc[4][4] = {};
  const int srow0 = tid >> 2, scol = tid & 3;
  const int srow1 = (tid + 256) >> 2;
  for (int k0 = 0; k0 < 1024; k0 += 32) {
    ushort8 a0 = *(const ushort8*)&A [(size_t)(m0 + srow0)*1024 + k0 + scol*8];
    ushort8 b0 = *(const ushort8*)&Bt[(size_t)(n0 + srow0)*1024 + k0 + scol*8];
    ushort8 a1 = *(const ushort8*)&A [(size_t)(m0 + srow1)*1024 + k0 + scol*8];
    ushort8 b1 = *(const ushort8*)&Bt[(size_t)(n0 + srow1)*1024 + k0 + scol*8];
    __syncthreads();
    *(ushort8*)&As[srow0*32 + scol*8] = a0;
    *(ushort8*)&Bs[srow0*32 + scol*8] = b0;
    *(ushort8*)&As[srow1*32 + scol*8] = a1;
    *(ushort8*)&Bs[srow1*32 + scol*8] = b1;
    __syncthreads();
    short8 af[4], bfr[4];
    #pragma unroll
    for (int i = 0; i < 4; ++i) af[i]  = lds8(&As[(wm*64 + i*16 + l15)*32 + quad*8]);
    #pragma unroll
    for (int j = 0; j < 4; ++j) bfr[j] = lds8(&Bs[(wn*64 + j*16 + l15)*32 + quad*8]);
    #pragma unroll
    for (int i = 0; i < 4; ++i)
      #pragma unroll
      for (int j = 0; j < 4; ++j)
        acc[i][j] = MFMA(af[i], bfr[j], acc[i][j]);
  }
  const int q4 = quad*4;
  #pragma unroll
  for (int i = 0; i < 4; ++i)
    #pragma unroll
    for (int j = 0; j < 4; ++j)
      #pragma unroll
      for (int r = 0; r < 4; ++r)
        C[(size_t)(m0 + wm*64 + i*16 + q4 + r)*ldc + n0 + wn*64 + j*16 + l15]
          = f2bf(acc[i][j][r]);
}

// ---------------------------------------------------------------------------
// attn: 256 blocks x 512 threads. 8 waves, wave c owns heads {2c, 2c+1} and
// out-column slice [c*128, c*128+128). q-tile = 16 rows, kv-tile = 32 keys.
// ---------------------------------------------------------------------------
// LDS layout (bytes):
#define L_XMT 0                 // 8 waves * [128 d][40 u16] = 81920 (pass2 x^T)
                                //   overlays: qrt 8*[16][136]u16=34816 (prologue)
                                //             ol  [16][1040]u16 =33280 (epilogue)
#define L_PRT 81920             // 16 heads * [16 q][40 u16] = 20480
#define L_PSP 102400            // 8 waves * [16 q][36 f32]  = 18432
#define L_PSA 120832            // [16 q][40 u16]            = 1280
#define L_DG  122112            // 16 f32                    = 64
#define L_SZ  122176

__global__ __launch_bounds__(512) void attn_k(
    const u16* __restrict__ x, const u16* __restrict__ wq,
    const u16* __restrict__ wo, const u16* __restrict__ wkwq,
    const u16* __restrict__ wvwo, const u16* __restrict__ K16,
    const u16* __restrict__ Vb0, const u16* __restrict__ Vb1a,
    const u16* __restrict__ Vb1b, float* out)
{
  __shared__ __align__(16) u8 AR[L_SZ];
  const int tid = threadIdx.x;
  const int lane = tid & 63, c = tid >> 6;          // wave 0..7
  const int l15 = lane & 15, quad = lane >> 4, q4 = quad*4;
  const int bb = blockIdx.x;
  const int b = bb >> 7, n0 = (bb & 127) * 16;
  const size_t xbase = (size_t)b * Nx * Dx;
  const u16* xxt = (const u16*)out;                 // bf16 XXT [2][2048][2048]
  const size_t xxbase = (size_t)b * Nx * Nx;

  u16*   xmt = (u16*)(AR + L_XMT) + c * (128*40);   // wave-private x^T slice
  u16*   qrt = (u16*)(AR + L_XMT) + c * (16*136);   // prologue overlay
  u16*   prt = (u16*)(AR + L_PRT);
  float* psp = (float*)(AR + L_PSP);
  u16*   psa = (u16*)(AR + L_PSA);
  float* dgv = (float*)(AR + L_DG);

  // ---- prologue: build Q frags (Q = x @ wq^T, this wave's 128 cols) ----
  {
    f32x4 qacc[8] = {};
    #pragma unroll 1
    for (int kc = 0; kc < 32; ++kc) {
      short8 af = *(const short8*)&x[xbase + (size_t)(n0 + l15)*Dx + kc*32 + quad*8];
      #pragma unroll
      for (int j = 0; j < 8; ++j) {
        short8 bf = *(const short8*)&wq[(size_t)(c*128 + j*16 + l15)*Dx + kc*32 + quad*8];
        qacc[j] = MFMA(af, bf, qacc[j]);
      }
    }
    #pragma unroll
    for (int j = 0; j < 8; ++j)
      #pragma unroll
      for (int r = 0; r < 4; ++r)
        qrt[(q4+r)*136 + j*16 + l15] = f2bf(qacc[j][r]);
  }
  // ---- prologue: exact diagonal of x@x^T for this block's 16 rows ----
  {
    int row = 2*c + (lane >> 5);
    int ch = lane & 31;
    float s = 0.f;
    #pragma unroll
    for (int p = 0; p < 4; ++p) {
      short8 v = *(const short8*)&x[xbase + (size_t)(n0+row)*Dx + p*256 + ch*8];
      #pragma unroll
      for (int i = 0; i < 8; ++i) { float f = bf2f((u16)v[i]); s += f*f; }
    }
    #pragma unroll
    for (int o = 1; o < 32; o <<= 1) s += __shfl_xor(s, o);
    if ((lane & 31) == 0) dgv[row] = s;
  }
  __syncthreads();
  short8 qf[2][2];
  #pragma unroll
  for (int hh = 0; hh < 2; ++hh)
    #pragma unroll
    for (int s = 0; s < 2; ++s)
      qf[hh][s] = lds8(&qrt[l15*136 + hh*64 + s*32 + quad*8]);
  float dv[4];
  #pragma unroll
  for (int r = 0; r < 4; ++r) dv[r] = dgv[q4+r];
  __syncthreads();   // qrt region is reused as xmt in pass 2

  float wkh[2], wvh[2];
  #pragma unroll
  for (int hh = 0; hh < 2; ++hh){ wkh[hh] = bf2f(wkwq[c*2+hh]); wvh[hh] = bf2f(wvwo[c*2+hh]); }

  // ---- pass 1: exact softmax stats (no LDS, no barriers) ----
  float mrun[2][4], lrun[2][4];
  #pragma unroll
  for (int hh=0;hh<2;++hh)
    #pragma unroll
    for (int r=0;r<4;++r){ mrun[hh][r] = -1e30f; lrun[hh][r] = 0.f; }

  #pragma unroll 1
  for (int mt = 0; mt < 64; ++mt) {
    u16 xb[2][4];
    #pragma unroll
    for (int s=0;s<2;++s)
      #pragma unroll
      for (int r=0;r<4;++r)
        xb[s][r] = xxt[xxbase + (size_t)(n0+q4+r)*Nx + mt*32 + s*16 + l15];
    short8 kf[2][2][2];
    #pragma unroll
    for (int hh=0;hh<2;++hh)
      #pragma unroll
      for (int s=0;s<2;++s)
        #pragma unroll
        for (int k2=0;k2<2;++k2)
          kf[hh][s][k2] = *(const short8*)&K16[xbase + (size_t)(mt*32+s*16+l15)*Dx + (c*2+hh)*64 + k2*32 + quad*8];
    f32x4 t2[2][2];
    #pragma unroll
    for (int hh=0;hh<2;++hh)
      #pragma unroll
      for (int s=0;s<2;++s){
        f32x4 t = {};
        t = MFMA(qf[hh][0], kf[hh][s][0], t);
        t = MFMA(qf[hh][1], kf[hh][s][1], t);
        t2[hh][s] = t;
      }
    #pragma unroll
    for (int hh=0;hh<2;++hh)
      #pragma unroll
      for (int r=0;r<4;++r){
        const int ng = n0 + q4 + r;
        float b0 = (mt*32      + l15 == ng) ? dv[r] : bf2f(xb[0][r]);
        float b1 = (mt*32 + 16 + l15 == ng) ? dv[r] : bf2f(xb[1][r]);
        float sv0 = SCALEx*t2[hh][0][r] + wkh[hh]*b0;
        float sv1 = SCALEx*t2[hh][1][r] + wkh[hh]*b1;
        float mx = fmaxf(sv0, sv1);
        #pragma unroll
        for (int o=1;o<16;o<<=1) mx = fmaxf(mx, __shfl_xor(mx, o));
        float mnew = fmaxf(mrun[hh][r], mx);
        float e = __expf(fminf(sv0-mnew,0.f)) + __expf(fminf(sv1-mnew,0.f));
        #pragma unroll
        for (int o=1;o<16;o<<=1) e += __shfl_xor(e, o);
        lrun[hh][r] = lrun[hh][r]*__expf(fminf(mrun[hh][r]-mnew,0.f)) + e;
        mrun[hh][r] = mnew;
      }
  }
  float ms[2][4], il[2][4];
  #pragma unroll
  for (int hh=0;hh<2;++hh)
    #pragma unroll
    for (int r=0;r<4;++r){ ms[hh][r] = mrun[hh][r]; il[hh][r] = 1.0f/fmaxf(lrun[hh][r],1e-30f); }

  // ---- pass 2: O (per-head) and U (PS @ x) ----
  f32x4 O[2][4] = {};
  f32x4 U[8] = {};
  const u16* vb = (b == 0) ? Vb0 : ((c < 4) ? Vb1a : Vb1b);
  const int dof = (b == 1 && c >= 4) ? 512 : 0;

  #pragma unroll 1
  for (int mt = 0; mt < 64; ++mt) {
    // -- global loads (all used-once; L2 resident) --
    u16 xb[2][4];
    #pragma unroll
    for (int s=0;s<2;++s)
      #pragma unroll
      for (int r=0;r<4;++r)
        xb[s][r] = xxt[xxbase + (size_t)(n0+q4+r)*Nx + mt*32 + s*16 + l15];
    short8 kf[2][2][2];
    #pragma unroll
    for (int hh=0;hh<2;++hh)
      #pragma unroll
      for (int s=0;s<2;++s)
        #pragma unroll
        for (int k2=0;k2<2;++k2)
          kf[hh][s][k2] = *(const short8*)&K16[xbase + (size_t)(mt*32+s*16+l15)*Dx + (c*2+hh)*64 + k2*32 + quad*8];
    short8 vf[2][4];
    #pragma unroll
    for (int hh=0;hh<2;++hh)
      #pragma unroll
      for (int dt=0;dt<4;++dt)
        vf[hh][dt] = *(const short8*)&vb[(size_t)((c*2+hh)*64 + dt*16 + l15 - dof)*Nx + mt*32 + quad*8];
    short8 a0[4], a1[4];
    #pragma unroll
    for (int i=0;i<4;++i){
      int m2 = (lane >> 4)*2 + i*8;
      a0[i] = *(const short8*)&x[xbase + (size_t)(mt*32 + m2    )*Dx + c*128 + l15*8];
      a1[i] = *(const short8*)&x[xbase + (size_t)(mt*32 + m2 + 1)*Dx + c*128 + l15*8];
    }
    // -- QK^T --
    f32x4 t2[2][2];
    #pragma unroll
    for (int hh=0;hh<2;++hh)
      #pragma unroll
      for (int s=0;s<2;++s){
        f32x4 t = {};
        t = MFMA(qf[hh][0], kf[hh][s][0], t);
        t = MFMA(qf[hh][1], kf[hh][s][1], t);
        t2[hh][s] = t;
      }
    // -- softmax apply + P/PS stores --
    float ps_[2][4] = {};
    #pragma unroll
    for (int hh=0;hh<2;++hh)
      #pragma unroll
      for (int s=0;s<2;++s)
        #pragma unroll
        for (int r=0;r<4;++r){
          const int ng = n0 + q4 + r;
          float bias = (mt*32 + s*16 + l15 == ng) ? dv[r] : bf2f(xb[s][r]);
          float sv = SCALEx*t2[hh][s][r] + wkh[hh]*bias;
          float p = __expf(fminf(sv - ms[hh][r], 0.f)) * il[hh][r];
          prt[(c*2+hh)*640 + (q4+r)*40 + s*16 + l15] = f2bf(p);
          ps_[s][r] += wvh[hh]*p;
        }
    #pragma unroll
    for (int s=0;s<2;++s)
      #pragma unroll
      for (int r=0;r<4;++r)
        psp[c*576 + (q4+r)*36 + s*16 + l15] = ps_[s][r];
    // -- stage x^T slice [128 d][32 m], wave-private, m-block swizzled --
    #pragma unroll
    for (int i=0;i<4;++i){
      int m2 = (lane >> 4)*2 + i*8;
      int sw = (l15 & 3) << 3;              // == ((dl>>3)&3)<<3 since dl = l15*8+j
      #pragma unroll
      for (int j=0;j<8;++j){
        int dl = l15*8 + j;
        *(u32*)&xmt[dl*40 + (m2 ^ sw)] = (u32)(u16)a0[i][j] | ((u32)(u16)a1[i][j] << 16);
      }
    }
    // -- PV (prt is wave-private: no barrier needed) --
    #pragma unroll
    for (int hh=0;hh<2;++hh){
      short8 pf = lds8(&prt[(c*2+hh)*640 + l15*40 + quad*8]);
      #pragma unroll
      for (int dt=0;dt<4;++dt)
        O[hh][dt] = MFMA(pf, vf[hh][dt], O[hh][dt]);
    }
    __syncthreads();                        // psp ready
    {
      float v = 0.f;
      #pragma unroll
      for (int w=0;w<8;++w) v += psp[w*576 + (tid>>5)*36 + (tid&31)];
      psa[(tid>>5)*40 + (tid&31)] = f2bf(v);
    }
    __syncthreads();                        // psa ready
    short8 psf = lds8(&psa[l15*40 + quad*8]);
    #pragma unroll
    for (int ct=0;ct<8;++ct){
      int d = ct*16 + l15;
      int sw = ((d >> 3) & 3) << 3;
      short8 xf = lds8(&xmt[d*40 + ((quad*8) ^ sw)]);
      U[ct] = MFMA(psf, xf, U[ct]);
    }
  }

  // ---- epilogue: U += O @ wo^T (ol overlays xmt region), fp32 store ----
  __syncthreads();
  u16* ol = (u16*)(AR + L_XMT);             // [16 q][1040 u16]
  #pragma unroll
  for (int hh=0;hh<2;++hh)
    #pragma unroll
    for (int dt=0;dt<4;++dt)
      #pragma unroll
      for (int r=0;r<4;++r)
        ol[(q4+r)*1040 + (c*2+hh)*64 + dt*16 + l15] = f2bf(O[hh][dt][r]);
  __syncthreads();
  #pragma unroll 1
  for (int kc = 0; kc < 32; ++kc) {
    short8 af = lds8(&ol[l15*1040 + kc*32 + quad*8]);
    #pragma unroll
    for (int ct=0;ct<8;++ct){
      short8 bfw = *(const short8*)&wo[(size_t)(c*128 + ct*16 + l15)*Dx + kc*32 + quad*8];
      U[ct] = MFMA(af, bfw, U[ct]);
    }
  }
  #pragma unroll
  for (int ct=0;ct<8;++ct)
    #pragma unroll
    for (int r=0;r<4;++r)
      out[xbase + (size_t)(n0+q4+r)*Dx + c*128 + ct*16 + l15] = U[ct][r];
}

// ---------------------------------------------------------------------------
extern "C" void kernel_launch(void* const* d_in, const int* in_sizes, int n_in,
                              void* d_out, int out_size, void* d_ws, size_t ws_size,
                              hipStream_t stream) {
  // fp32 input buffers; after conversion the front half of each holds bf16,
  // the back half becomes scratch:
  //   d_in[0]: x16 (8MB) | K16 (8MB)
  //   d_in[1]: wqk16 (4MB) | Vt_b0 (4MB)        Vt = V^T, [1024 d][2048 m]
  //   d_in[2]: wv16 (2MB) | Vt_b1 d<512 (2MB)
  //   d_in[3]: wo16 (2MB) | Vt_b1 d>=512 (2MB)
  //   d_out  : conv scratch, then XXT bf16 [2][2048][2048], then final fp32 out
  u16* x16   = (u16*)d_in[0];
  u16* K16   = x16 + 4u*1024u*1024u;
  u16* wqk16 = (u16*)d_in[1];
  u16* Vb0   = wqk16 + 2u*1024u*1024u;
  u16* wv16  = (u16*)d_in[2];
  u16* Vb1a  = wv16 + 1024u*1024u;
  u16* wo16  = (u16*)d_in[3];
  u16* Vb1b  = wo16 + 1024u*1024u;
  float* outF = (float*)d_out;
  u16* S = (u16*)d_out;                          // conversion scratch (pre-XXT)

  const float loW = 0.000244140625f, hiW = 0.25f;
  conv_w<<<dim3(512), 256, 0, stream>>>(d_in[0], S, 4*1024*1024, 512, 0.00390625f, 16.0f);
  copyb <<<dim3(512), 256, 0, stream>>>(S, x16, 4*1024*1024);
  conv_w<<<dim3(256), 256, 0, stream>>>(d_in[1], S, 2*1024*1024, 512, loW, hiW);
  copyb <<<dim3(256), 256, 0, stream>>>(S, wqk16, 2*1024*1024);
  conv_w<<<dim3(128), 256, 0, stream>>>(d_in[2], S, 1024*1024, 512, loW, hiW);
  copyb <<<dim3(128), 256, 0, stream>>>(S, wv16, 1024*1024);
  conv_w<<<dim3(128), 256, 0, stream>>>(d_in[3], S, 1024*1024, 512, loW, hiW);
  copyb <<<dim3(128), 256, 0, stream>>>(S, wo16, 1024*1024);
  conv_small<<<dim3(1), 64, 0, stream>>>((void*)d_in[4], 16, loW, hiW);
  conv_small<<<dim3(1), 64, 0, stream>>>((void*)d_in[5], 16, loW, hiW);

  // K = x @ wk^T (both batches, 4096 rows)
  gemm_bf16<<<dim3(8, 32), 256, 0, stream>>>(x16, wqk16 + 1024u*1024u, K16, 1024);
  // Vt = wv @ x^T : plain NT GEMM (A = wv rows = d, Bt = x rows = tokens)
  gemm_bf16<<<dim3(16, 8), 256, 0, stream>>>(wv16, x16, Vb0, 2048);                                  // b0, d 0..1023
  gemm_bf16<<<dim3(16, 4), 256, 0, stream>>>(wv16,               x16 + 2048u*1024u, Vb1a, 2048);     // b1, d 0..511
  gemm_bf16<<<dim3(16, 4), 256, 0, stream>>>(wv16 + 512u*1024u,  x16 + 2048u*1024u, Vb1b, 2048);     // b1, d 512..1023
  // XXT = x @ x^T (bf16) into d_out
  gemm_bf16<<<dim3(16, 16), 256, 0, stream>>>(x16,               x16,               (u16*)d_out,                      2048);
  gemm_bf16<<<dim3(16, 16), 256, 0, stream>>>(x16 + 2048u*1024u, x16 + 2048u*1024u, (u16*)d_out + 4u*1024u*1024u,     2048);
  // fused attention (reads its own XXT rows, overwrites them with fp32 out)
  attn_k<<<dim3(256), 512, 0, stream>>>(x16, wqk16, wo16,
      (const u16*)d_in[4], (const u16*)d_in[5], K16, Vb0, Vb1a, Vb1b, outF);
}